// Round 7
// baseline (372.377 us; speedup 1.0000x reference)
//
#include <hip/hip_runtime.h>
#include <hip/hip_bf16.h>
#include <math.h>

// Problem constants (B=8, C=128, N=1024, UP=4)
#define BB    8
#define CC    128
#define NN    1024
#define MM    4096     // UP*N
#define CIN   130      // C+2
#define NROWS 194      // 32 f + 32 g + 130 h
#define CIN_P 160      // padded channel count (130 -> 160 = 5 K-slices of 32)
#define OPAD  208      // padded fgh output rows (13 tiles of 16)

// ---- Layouts (bf16 unless noted) ------------------------------------------
// net_t [B*M][160] : transposed+padded input (c-fastest), grid cols fused
// f_t   [B*M][32]  : f transposed   g_t [B*M][32] : g transposed
// h     [B][130][M]: row-major
// Lsum  [B][M] f32 : sum_m exp(s[k,m]-4)   (atomic-accumulated)
// P     [2][B][130][M] f32 : k-split partial O
// x_t   [B*M][160] : attn+residual (pad cols zeroed)
// x1_t  [B*M][256] : conv1 out (ALIASES P — P dead after combine)
// Wfgh  [208][160], W1b [256][160], W2b [128][256], bfgh f32[208]
// ---------------------------------------------------------------------------

typedef __attribute__((ext_vector_type(8))) short   bf16x8;
typedef __attribute__((ext_vector_type(4))) float   f32x4;
typedef __attribute__((ext_vector_type(8))) unsigned short u16x8;
typedef __attribute__((ext_vector_type(4))) unsigned short u16x4;

static __device__ __forceinline__ unsigned short f2bf(float f) {
    union { float f; unsigned u; } v; v.f = f;
    unsigned r = v.u + 0x7FFFu + ((v.u >> 16) & 1u);   // RNE, finite inputs
    return (unsigned short)(r >> 16);
}
static __device__ __forceinline__ float bf2f(unsigned short s) {
    union { unsigned u; float f; } v; v.u = ((unsigned)s) << 16;
    return v.f;
}

#define MFMA16(a, b, c) __builtin_amdgcn_mfma_f32_16x16x32_bf16((a), (b), (c), 0, 0, 0)

// ---------------------------------------------------------------------------
// K0: prep — pack/pad all weights to bf16, zero Lsum.
// ---------------------------------------------------------------------------
__global__ __launch_bounds__(256) void prep_kernel(
    const float* __restrict__ W1, const float* __restrict__ W2,
    const float* __restrict__ WF, const float* __restrict__ WG,
    const float* __restrict__ WH, const float* __restrict__ bFp,
    const float* __restrict__ bGp, const float* __restrict__ bHp,
    unsigned short* __restrict__ W1b, unsigned short* __restrict__ W2b,
    unsigned short* __restrict__ Wfgh, float* __restrict__ bfgh,
    float* __restrict__ Lsum)
{
    int i = blockIdx.x * 256 + threadIdx.x;
    if (i < 40960) {
        int o = i / CIN_P, c = i - o * CIN_P;
        W1b[i] = (c < CIN) ? f2bf(W1[o * CIN + c]) : (unsigned short)0;
    } else if (i < 73728) {
        int j = i - 40960;
        W2b[j] = f2bf(W2[j]);
    } else if (i < 107008) {
        int j = i - 73728;
        int o = j / CIN_P, c = j - o * CIN_P;
        float w = 0.f;
        if (c < CIN) {
            if (o < 32)         w = WF[o * CIN + c];
            else if (o < 64)    w = WG[(o - 32) * CIN + c];
            else if (o < NROWS) w = WH[(o - 64) * CIN + c];
        }
        Wfgh[j] = f2bf(w);
    } else if (i < 107216) {
        int o = i - 107008;
        float bv = 0.f;
        if (o < 32)         bv = bFp[o];
        else if (o < 64)    bv = bGp[o - 32];
        else if (o < NROWS) bv = bHp[o - 64];
        bfgh[o] = bv;
    } else if (i < 139984) {
        Lsum[i - 107216] = 0.f;
    }
}

// ---------------------------------------------------------------------------
// K1: transpose — inp [B][128][1024] f32 -> net_t [B*M][160] bf16
// ---------------------------------------------------------------------------
__global__ __launch_bounds__(256) void transpose_kernel(
    const float* __restrict__ inp, unsigned short* __restrict__ net_t)
{
    const int b  = blockIdx.y;
    const int n0 = blockIdx.x * 32;
    const int t  = threadIdx.x;

    __shared__ float tile[CC][33];

    for (int idx = t; idx < CC * 32; idx += 256) {
        int c = idx >> 5, n = idx & 31;
        tile[c][n] = inp[((size_t)b * CC + c) * NN + n0 + n];
    }
    __syncthreads();

    const int n = t >> 3, grp = t & 7;
    #pragma unroll
    for (int q = 0; q < 4; ++q) {
        const int m = q * NN + n0 + n;
        const float gx = (q >> 1) ? 0.2f : -0.2f;
        const float gy = (q & 1)  ? 0.2f : -0.2f;
        for (int j = grp; j < 20; j += 8) {
            const int c0 = j * 8;
            u16x8 pk;
            #pragma unroll
            for (int i = 0; i < 8; ++i) {
                int c = c0 + i;
                float v = (c < CC) ? tile[c][n]
                        : (c == CC) ? gx : (c == CC + 1) ? gy : 0.f;
                pk[i] = f2bf(v);
            }
            *(u16x8*)&net_t[((size_t)b * MM + m) * CIN_P + c0] = pk;
        }
    }
}

// ---------------------------------------------------------------------------
// K2: proj — fgh = relu(Wfgh @ net + b) via MFMA. No LDS, no barriers.
// ---------------------------------------------------------------------------
__global__ __launch_bounds__(256) void proj_kernel(
    const unsigned short* __restrict__ Wfgh, const float* __restrict__ bfgh,
    const unsigned short* __restrict__ net_t,
    unsigned short* __restrict__ f_t, unsigned short* __restrict__ g_t,
    unsigned short* __restrict__ h)
{
    const int lane = threadIdx.x & 63, w = threadIdx.x >> 6;
    const int l15 = lane & 15, lg = lane >> 4;
    const int mg = blockIdx.x * 64 + w * 16 + l15;   // over B*M
    const int b = mg >> 12, m = mg & (MM - 1);

    bf16x8 nf[5];
    #pragma unroll
    for (int ks = 0; ks < 5; ++ks)
        nf[ks] = *(const bf16x8*)&net_t[(size_t)mg * CIN_P + ks * 32 + lg * 8];

    const f32x4 zero = {0.f, 0.f, 0.f, 0.f};

    #pragma unroll
    for (int ot = 0; ot < 13; ++ot) {
        f32x4 acc = zero;
        #pragma unroll
        for (int ks = 0; ks < 5; ++ks) {
            bf16x8 aW = *(const bf16x8*)&Wfgh[(size_t)(ot * 16 + l15) * CIN_P + ks * 32 + lg * 8];
            acc = MFMA16(aW, nf[ks], acc);
        }
        const int o0 = ot * 16 + lg * 4;
        float v[4];
        #pragma unroll
        for (int r = 0; r < 4; ++r) v[r] = fmaxf(acc[r] + bfgh[o0 + r], 0.f);

        if (ot < 2) {
            u16x4 pk;
            #pragma unroll
            for (int r = 0; r < 4; ++r) pk[r] = f2bf(v[r]);
            *(u16x4*)&f_t[(size_t)mg * 32 + o0] = pk;
        } else if (ot < 4) {
            u16x4 pk;
            #pragma unroll
            for (int r = 0; r < 4; ++r) pk[r] = f2bf(v[r]);
            *(u16x4*)&g_t[(size_t)mg * 32 + (o0 - 32)] = pk;
        } else {
            #pragma unroll
            for (int r = 0; r < 4; ++r) {
                int o = o0 + r;
                if (o < NROWS)
                    h[((size_t)b * CIN + (o - 64)) * MM + m] = f2bf(v[r]);
            }
        }
    }
}

// ---------------------------------------------------------------------------
// K3: rowstats — Lsum[k] += sum_{m in split} exp(s[k,m]-4), m-split=4, atomic.
// ---------------------------------------------------------------------------
__global__ __launch_bounds__(256) void rowstats_kernel(
    const unsigned short* __restrict__ f_t, const unsigned short* __restrict__ g_t,
    float* __restrict__ Lsum)
{
    const int b  = blockIdx.y;
    const int k0 = blockIdx.x * 64;
    const int m0 = blockIdx.z * 1024;
    const int lane = threadIdx.x & 63, w = threadIdx.x >> 6;
    const int l15 = lane & 15, lg = lane >> 4;

    const bf16x8 aG = *(const bf16x8*)&g_t[((size_t)b * MM + k0 + w * 16 + l15) * 32 + lg * 8];
    const f32x4 zero = {0.f, 0.f, 0.f, 0.f};
    f32x4 sum = zero;

    for (int mc = m0; mc < m0 + 1024; mc += 64) {
        #pragma unroll
        for (int mt = 0; mt < 4; ++mt) {
            bf16x8 fB = *(const bf16x8*)&f_t[((size_t)b * MM + mc + mt * 16 + l15) * 32 + lg * 8];
            f32x4 s = MFMA16(aG, fB, zero);
            #pragma unroll
            for (int r = 0; r < 4; ++r) sum[r] += __expf(s[r] - 4.0f);
        }
    }

    #pragma unroll
    for (int d = 1; d < 16; d <<= 1) {
        #pragma unroll
        for (int r = 0; r < 4; ++r) sum[r] += __shfl_xor(sum[r], d);
    }
    if (l15 == 0) {
        #pragma unroll
        for (int r = 0; r < 4; ++r)
            atomicAdd(&Lsum[b * MM + k0 + w * 16 + lg * 4 + r], sum[r]);
    }
}

// ---------------------------------------------------------------------------
// K4: attn — no H staging, no barriers. Block = 128 m (4 waves x 32 m),
// k-split=2 over blockIdx.z. H A-frags direct from global (L1/L2-resident).
// E bounce through per-wave private 4KB LDS slice, XOR-swizzled
// (elem ^= (l15&7)<<3), fenced by lgkmcnt(0)+sched_barrier (no syncthreads).
// ---------------------------------------------------------------------------
__global__ __launch_bounds__(256) void attn_kernel(
    const unsigned short* __restrict__ f_t, const unsigned short* __restrict__ g_t,
    const unsigned short* __restrict__ h,   const float* __restrict__ Lsum,
    float* __restrict__ P)
{
    const int b  = blockIdx.y;
    const int m0 = blockIdx.x * 128;
    const int kz = blockIdx.z;
    const int tid = threadIdx.x;
    const int lane = tid & 63, w = tid >> 6;
    const int l15 = lane & 15, lg = lane >> 4;

    __shared__ unsigned short Et[4 * 2048];    // 16 KB: per-wave 32m x 64k
    unsigned short* et = &Et[w * 2048];
    const int swzx = (l15 & 7) << 3;

    const f32x4 zero = {0.f, 0.f, 0.f, 0.f};

    // persistent F B-frags for this wave's 2 m-tiles
    bf16x8 fF[2];
    #pragma unroll
    for (int mt = 0; mt < 2; ++mt)
        fF[mt] = *(const bf16x8*)&f_t[((size_t)b * MM + m0 + w * 32 + mt * 16 + l15) * 32 + lg * 8];

    f32x4 acc[9][2];
    #pragma unroll
    for (int ct = 0; ct < 9; ++ct)
        #pragma unroll
        for (int mt = 0; mt < 2; ++mt) acc[ct][mt] = zero;

    const int kbeg = kz * (MM / 2), kend = kbeg + (MM / 2);
    for (int kc = kbeg; kc < kend; kc += 64) {
        // ---- S phase: 8 MFMAs, E -> private LDS slice --------------------
        bf16x8 aG[4];
        #pragma unroll
        for (int kt = 0; kt < 4; ++kt)
            aG[kt] = *(const bf16x8*)&g_t[((size_t)b * MM + kc + kt * 16 + l15) * 32 + lg * 8];
        f32x4 rv[4];
        #pragma unroll
        for (int kt = 0; kt < 4; ++kt) {
            f32x4 ls = *(const f32x4*)&Lsum[b * MM + kc + kt * 16 + lg * 4];
            #pragma unroll
            for (int r = 0; r < 4; ++r) rv[kt][r] = __builtin_amdgcn_rcpf(ls[r]);
        }
        #pragma unroll
        for (int mt = 0; mt < 2; ++mt) {
            #pragma unroll
            for (int kt = 0; kt < 4; ++kt) {
                f32x4 s = MFMA16(aG[kt], fF[mt], zero);
                u16x4 pk;
                #pragma unroll
                for (int r = 0; r < 4; ++r)
                    pk[r] = f2bf(__expf(s[r] - 4.0f) * rv[kt][r]);
                *(u16x4*)&et[(mt * 16 + l15) * 64 + ((kt * 16 + lg * 4) ^ swzx)] = pk;
            }
        }

        // wave-private LDS fence (cross-lane read of own wave's writes)
        asm volatile("s_waitcnt lgkmcnt(0)" ::: "memory");
        __builtin_amdgcn_sched_barrier(0);

        bf16x8 eB[2][2];
        #pragma unroll
        for (int mt = 0; mt < 2; ++mt)
            #pragma unroll
            for (int ks = 0; ks < 2; ++ks)
                eB[mt][ks] = *(const bf16x8*)&et[(mt * 16 + l15) * 64 + ((ks * 32 + lg * 8) ^ swzx)];

        // ---- O phase: H A-frags from global, 36 MFMAs --------------------
        #pragma unroll
        for (int ct = 0; ct < 9; ++ct) {
            const int c = ct * 16 + l15;
            #pragma unroll
            for (int ks = 0; ks < 2; ++ks) {
                bf16x8 aH = {0,0,0,0,0,0,0,0};
                if (c < CIN)
                    aH = *(const bf16x8*)&h[((size_t)b * CIN + c) * MM + kc + ks * 32 + lg * 8];
                #pragma unroll
                for (int mt = 0; mt < 2; ++mt)
                    acc[ct][mt] = MFMA16(aH, eB[mt][ks], acc[ct][mt]);
            }
        }
    }

    // partial store: P[kz][b][c][m]
    #pragma unroll
    for (int ct = 0; ct < 9; ++ct) {
        #pragma unroll
        for (int mt = 0; mt < 2; ++mt) {
            const int m = m0 + w * 32 + mt * 16 + l15;
            #pragma unroll
            for (int r = 0; r < 4; ++r) {
                const int c = ct * 16 + lg * 4 + r;
                if (c < CIN)
                    P[((size_t)(kz * BB + b) * CIN + c) * MM + m] = acc[ct][mt][r];
            }
        }
    }
}

// ---------------------------------------------------------------------------
// K5: combine — x_t = gamma*(P0+P1) + net_t (pad cols -> 0)
// ---------------------------------------------------------------------------
__global__ __launch_bounds__(256) void combine_kernel(
    const float* __restrict__ P, const unsigned short* __restrict__ net_t,
    const float* __restrict__ gamma_p, unsigned short* __restrict__ x_t)
{
    const int b = blockIdx.y;
    const int moff = threadIdx.x & 63, cg = threadIdx.x >> 6;
    const int m = blockIdx.x * 64 + moff;
    const float gam = gamma_p[0];

    #pragma unroll
    for (int j = 0; j < 5; ++j) {
        const int c0 = cg * 40 + j * 8;
        u16x8 net8 = *(const u16x8*)&net_t[((size_t)b * MM + m) * CIN_P + c0];
        u16x8 pk;
        #pragma unroll
        for (int i = 0; i < 8; ++i) {
            const int c = c0 + i;
            if (c < CIN) {
                float p0 = P[((size_t)(0 * BB + b) * CIN + c) * MM + m];
                float p1 = P[((size_t)(1 * BB + b) * CIN + c) * MM + m];
                pk[i] = f2bf(gam * (p0 + p1) + bf2f(net8[i]));
            } else {
                pk[i] = 0;
            }
        }
        *(u16x8*)&x_t[((size_t)b * MM + m) * CIN_P + c0] = pk;
    }
}

// ---------------------------------------------------------------------------
// K6/K7: conv1x1 + relu via MFMA
// ---------------------------------------------------------------------------
template <int KS, int OT, bool OUTF32>
__global__ __launch_bounds__(256) void conv_mfma_kernel(
    const unsigned short* __restrict__ Wb, const float* __restrict__ bias,
    const unsigned short* __restrict__ in_t,
    unsigned short* __restrict__ out_bf, float* __restrict__ out_f32)
{
    const int CINP = KS * 32;
    const int lane = threadIdx.x & 63, w = threadIdx.x >> 6;
    const int l15 = lane & 15, lg = lane >> 4;
    const int m = blockIdx.x * 64 + w * 16 + l15;   // over B*M

    bf16x8 bFr[KS];
    #pragma unroll
    for (int ks = 0; ks < KS; ++ks)
        bFr[ks] = *(const bf16x8*)&in_t[(size_t)m * CINP + ks * 32 + lg * 8];

    const f32x4 zero = {0.f, 0.f, 0.f, 0.f};

    #pragma unroll
    for (int ot = 0; ot < OT; ++ot) {
        f32x4 acc = zero;
        #pragma unroll
        for (int ks = 0; ks < KS; ++ks) {
            bf16x8 aW = *(const bf16x8*)&Wb[(size_t)(ot * 16 + l15) * CINP + ks * 32 + lg * 8];
            acc = MFMA16(aW, bFr[ks], acc);
        }
        const int obase = ot * 16 + lg * 4;
        if (OUTF32) {
            const int bb = m >> 12, mm = m & (MM - 1);
            #pragma unroll
            for (int r = 0; r < 4; ++r)
                out_f32[((size_t)bb * (OT * 16) + obase + r) * MM + mm] =
                    fmaxf(acc[r] + bias[obase + r], 0.f);
        } else {
            u16x4 pk;
            #pragma unroll
            for (int r = 0; r < 4; ++r)
                pk[r] = f2bf(fmaxf(acc[r] + bias[obase + r], 0.f));
            *(u16x4*)&out_bf[(size_t)m * (OT * 16) + obase] = pk;
        }
    }
}

// ---------------------------------------------------------------------------
extern "C" void kernel_launch(void* const* d_in, const int* in_sizes, int n_in,
                              void* d_out, int out_size, void* d_ws, size_t ws_size,
                              hipStream_t stream)
{
    const float* inp   = (const float*)d_in[0];
    const float* WF    = (const float*)d_in[1];
    const float* bF    = (const float*)d_in[2];
    const float* WG    = (const float*)d_in[3];
    const float* bG    = (const float*)d_in[4];
    const float* WH    = (const float*)d_in[5];
    const float* bH    = (const float*)d_in[6];
    const float* gamma = (const float*)d_in[7];
    const float* W1    = (const float*)d_in[8];
    const float* b1    = (const float*)d_in[9];
    const float* W2    = (const float*)d_in[10];
    const float* b2    = (const float*)d_in[11];
    float* out = (float*)d_out;

    char* p = (char*)d_ws;
    auto alloc = [&](size_t bytes) { char* q = p; p += (bytes + 255) & ~(size_t)255; return q; };
    unsigned short* net_t = (unsigned short*)alloc((size_t)BB * MM * CIN_P * 2);  // 10.5 MB
    unsigned short* f_t   = (unsigned short*)alloc((size_t)BB * MM * 32 * 2);     //  2.1 MB
    unsigned short* g_t   = (unsigned short*)alloc((size_t)BB * MM * 32 * 2);     //  2.1 MB
    unsigned short* h     = (unsigned short*)alloc((size_t)BB * CIN * MM * 2);    //  8.5 MB
    float*          Lsum  = (float*)alloc((size_t)BB * MM * 4);                   //  0.13 MB
    unsigned short* x_t   = (unsigned short*)alloc((size_t)BB * MM * CIN_P * 2);  // 10.5 MB
    float*          P     = (float*)alloc((size_t)2 * BB * CIN * MM * 4);         // 34.1 MB
    unsigned short* x1_t  = (unsigned short*)P;   // alias: P dead after combine
    unsigned short* W1b   = (unsigned short*)alloc((size_t)256 * CIN_P * 2);
    unsigned short* W2b   = (unsigned short*)alloc((size_t)128 * 256 * 2);
    unsigned short* Wfgh  = (unsigned short*)alloc((size_t)OPAD * CIN_P * 2);
    float*          bfgh  = (float*)alloc((size_t)OPAD * 4);

    prep_kernel<<<547, 256, 0, stream>>>(W1, W2, WF, WG, WH, bF, bG, bH,
                                         W1b, W2b, Wfgh, bfgh, Lsum);

    transpose_kernel<<<dim3(NN / 32, BB), 256, 0, stream>>>(inp, net_t);

    proj_kernel<<<dim3(BB * MM / 64), 256, 0, stream>>>(
        Wfgh, bfgh, net_t, f_t, g_t, h);

    rowstats_kernel<<<dim3(MM / 64, BB, 4), 256, 0, stream>>>(f_t, g_t, Lsum);

    attn_kernel<<<dim3(MM / 128, BB, 2), 256, 0, stream>>>(f_t, g_t, h, Lsum, P);

    combine_kernel<<<dim3(MM / 64, BB), 256, 0, stream>>>(P, net_t, gamma, x_t);

    conv_mfma_kernel<5, 16, false><<<dim3(BB * MM / 64), 256, 0, stream>>>(
        W1b, b1, x_t, x1_t, nullptr);

    conv_mfma_kernel<8, 8, true><<<dim3(BB * MM / 64), 256, 0, stream>>>(
        W2b, b2, x1_t, nullptr, out);
}

// Round 13
// 287.973 us; speedup vs baseline: 1.2931x; 1.2931x over previous
//
#include <hip/hip_runtime.h>
#include <hip/hip_bf16.h>
#include <math.h>

// Problem constants (B=8, C=128, N=1024, UP=4)
#define BB    8
#define CC    128
#define NN    1024
#define MM    4096     // UP*N
#define CIN   130      // C+2
#define NROWS 194      // 32 f + 32 g + 130 h
#define CIN_P 160      // padded channel count (130 -> 160 = 5 K-slices of 32)
#define OPAD  208      // padded fgh output rows (13 tiles of 16)

// ---- Layouts (bf16 unless noted) ------------------------------------------
// net_t [B*M][160] : transposed+padded input (c-fastest), grid cols fused
// f_t   [B*M][32]  : f transposed   g_t [B*M][32] : g transposed
// h     [B][130][M]: row-major
// Lsum  [B][M] f32 : sum_m exp(s[k,m]-4)   (atomic-accumulated)
// P     [2][B][130][M] f32 : k-split partial O
// x_t   [B*M][160] : attn+residual (pad cols zeroed)
// x1_t  [B*M][256] : conv1 out (ALIASES P — P dead after combine)
// Wfgh  [208][160], W1b [256][160], W2b [128][256], bfgh f32[208]
// ---------------------------------------------------------------------------

typedef __attribute__((ext_vector_type(8))) short   bf16x8;
typedef __attribute__((ext_vector_type(4))) float   f32x4;
typedef __attribute__((ext_vector_type(8))) unsigned short u16x8;
typedef __attribute__((ext_vector_type(4))) unsigned short u16x4;

static __device__ __forceinline__ unsigned short f2bf(float f) {
    union { float f; unsigned u; } v; v.f = f;
    unsigned r = v.u + 0x7FFFu + ((v.u >> 16) & 1u);   // RNE, finite inputs
    return (unsigned short)(r >> 16);
}
static __device__ __forceinline__ float bf2f(unsigned short s) {
    union { unsigned u; float f; } v; v.u = ((unsigned)s) << 16;
    return v.f;
}

#define MFMA16(a, b, c) __builtin_amdgcn_mfma_f32_16x16x32_bf16((a), (b), (c), 0, 0, 0)

// ---------------------------------------------------------------------------
// K0: prep — pack/pad all weights to bf16, zero Lsum.
// ---------------------------------------------------------------------------
__global__ __launch_bounds__(256) void prep_kernel(
    const float* __restrict__ W1, const float* __restrict__ W2,
    const float* __restrict__ WF, const float* __restrict__ WG,
    const float* __restrict__ WH, const float* __restrict__ bFp,
    const float* __restrict__ bGp, const float* __restrict__ bHp,
    unsigned short* __restrict__ W1b, unsigned short* __restrict__ W2b,
    unsigned short* __restrict__ Wfgh, float* __restrict__ bfgh,
    float* __restrict__ Lsum)
{
    int i = blockIdx.x * 256 + threadIdx.x;
    if (i < 40960) {
        int o = i / CIN_P, c = i - o * CIN_P;
        W1b[i] = (c < CIN) ? f2bf(W1[o * CIN + c]) : (unsigned short)0;
    } else if (i < 73728) {
        int j = i - 40960;
        W2b[j] = f2bf(W2[j]);
    } else if (i < 107008) {
        int j = i - 73728;
        int o = j / CIN_P, c = j - o * CIN_P;
        float w = 0.f;
        if (c < CIN) {
            if (o < 32)         w = WF[o * CIN + c];
            else if (o < 64)    w = WG[(o - 32) * CIN + c];
            else if (o < NROWS) w = WH[(o - 64) * CIN + c];
        }
        Wfgh[j] = f2bf(w);
    } else if (i < 107216) {
        int o = i - 107008;
        float bv = 0.f;
        if (o < 32)         bv = bFp[o];
        else if (o < 64)    bv = bGp[o - 32];
        else if (o < NROWS) bv = bHp[o - 64];
        bfgh[o] = bv;
    } else if (i < 139984) {
        Lsum[i - 107216] = 0.f;
    }
}

// ---------------------------------------------------------------------------
// K1: transpose — inp [B][128][1024] f32 -> net_t [B*M][160] bf16
// ---------------------------------------------------------------------------
__global__ __launch_bounds__(256) void transpose_kernel(
    const float* __restrict__ inp, unsigned short* __restrict__ net_t)
{
    const int b  = blockIdx.y;
    const int n0 = blockIdx.x * 32;
    const int t  = threadIdx.x;

    __shared__ float tile[CC][33];

    for (int idx = t; idx < CC * 32; idx += 256) {
        int c = idx >> 5, n = idx & 31;
        tile[c][n] = inp[((size_t)b * CC + c) * NN + n0 + n];
    }
    __syncthreads();

    const int n = t >> 3, grp = t & 7;
    #pragma unroll
    for (int q = 0; q < 4; ++q) {
        const int m = q * NN + n0 + n;
        const float gx = (q >> 1) ? 0.2f : -0.2f;
        const float gy = (q & 1)  ? 0.2f : -0.2f;
        for (int j = grp; j < 20; j += 8) {
            const int c0 = j * 8;
            u16x8 pk;
            #pragma unroll
            for (int i = 0; i < 8; ++i) {
                int c = c0 + i;
                float v = (c < CC) ? tile[c][n]
                        : (c == CC) ? gx : (c == CC + 1) ? gy : 0.f;
                pk[i] = f2bf(v);
            }
            *(u16x8*)&net_t[((size_t)b * MM + m) * CIN_P + c0] = pk;
        }
    }
}

// ---------------------------------------------------------------------------
// K2: proj — fgh = relu(Wfgh @ net + b) via MFMA. No LDS, no barriers.
// ---------------------------------------------------------------------------
__global__ __launch_bounds__(256) void proj_kernel(
    const unsigned short* __restrict__ Wfgh, const float* __restrict__ bfgh,
    const unsigned short* __restrict__ net_t,
    unsigned short* __restrict__ f_t, unsigned short* __restrict__ g_t,
    unsigned short* __restrict__ h)
{
    const int lane = threadIdx.x & 63, w = threadIdx.x >> 6;
    const int l15 = lane & 15, lg = lane >> 4;
    const int mg = blockIdx.x * 64 + w * 16 + l15;   // over B*M
    const int b = mg >> 12, m = mg & (MM - 1);

    bf16x8 nf[5];
    #pragma unroll
    for (int ks = 0; ks < 5; ++ks)
        nf[ks] = *(const bf16x8*)&net_t[(size_t)mg * CIN_P + ks * 32 + lg * 8];

    const f32x4 zero = {0.f, 0.f, 0.f, 0.f};

    #pragma unroll
    for (int ot = 0; ot < 13; ++ot) {
        f32x4 acc = zero;
        #pragma unroll
        for (int ks = 0; ks < 5; ++ks) {
            bf16x8 aW = *(const bf16x8*)&Wfgh[(size_t)(ot * 16 + l15) * CIN_P + ks * 32 + lg * 8];
            acc = MFMA16(aW, nf[ks], acc);
        }
        const int o0 = ot * 16 + lg * 4;
        float v[4];
        #pragma unroll
        for (int r = 0; r < 4; ++r) v[r] = fmaxf(acc[r] + bfgh[o0 + r], 0.f);

        if (ot < 2) {
            u16x4 pk;
            #pragma unroll
            for (int r = 0; r < 4; ++r) pk[r] = f2bf(v[r]);
            *(u16x4*)&f_t[(size_t)mg * 32 + o0] = pk;
        } else if (ot < 4) {
            u16x4 pk;
            #pragma unroll
            for (int r = 0; r < 4; ++r) pk[r] = f2bf(v[r]);
            *(u16x4*)&g_t[(size_t)mg * 32 + (o0 - 32)] = pk;
        } else {
            #pragma unroll
            for (int r = 0; r < 4; ++r) {
                int o = o0 + r;
                if (o < NROWS)
                    h[((size_t)b * CIN + (o - 64)) * MM + m] = f2bf(v[r]);
            }
        }
    }
}

// ---------------------------------------------------------------------------
// K3: rowstats — Lsum[k] += sum_{m in split} exp(s[k,m]-4), m-split=4, atomic.
// ---------------------------------------------------------------------------
__global__ __launch_bounds__(256) void rowstats_kernel(
    const unsigned short* __restrict__ f_t, const unsigned short* __restrict__ g_t,
    float* __restrict__ Lsum)
{
    const int b  = blockIdx.y;
    const int k0 = blockIdx.x * 64;
    const int m0 = blockIdx.z * 1024;
    const int lane = threadIdx.x & 63, w = threadIdx.x >> 6;
    const int l15 = lane & 15, lg = lane >> 4;

    const bf16x8 aG = *(const bf16x8*)&g_t[((size_t)b * MM + k0 + w * 16 + l15) * 32 + lg * 8];
    const f32x4 zero = {0.f, 0.f, 0.f, 0.f};
    f32x4 sum = zero;

    for (int mc = m0; mc < m0 + 1024; mc += 64) {
        #pragma unroll
        for (int mt = 0; mt < 4; ++mt) {
            bf16x8 fB = *(const bf16x8*)&f_t[((size_t)b * MM + mc + mt * 16 + l15) * 32 + lg * 8];
            f32x4 s = MFMA16(aG, fB, zero);
            #pragma unroll
            for (int r = 0; r < 4; ++r) sum[r] += __expf(s[r] - 4.0f);
        }
    }

    #pragma unroll
    for (int d = 1; d < 16; d <<= 1) {
        #pragma unroll
        for (int r = 0; r < 4; ++r) sum[r] += __shfl_xor(sum[r], d);
    }
    if (l15 == 0) {
        #pragma unroll
        for (int r = 0; r < 4; ++r)
            atomicAdd(&Lsum[b * MM + k0 + w * 16 + lg * 4 + r], sum[r]);
    }
}

// ---------------------------------------------------------------------------
// K4: attn — r5 pipelined 2-barrier structure + XOR-swizzled LDS + 128m block.
// Block = 128 m (4 waves x 32 m), kz-split=2, k-chunks of 64.
// Hs [144 rows][8 chunks of 16B] shared, chunk slot = seg ^ (row&7)
//   (conflict-free b128 write AND read; row stride 64 units = 128 B).
// Et per-wave private [32m][64k], elem ^= (l15&7)<<3      (r7-proven).
// Per iter: issue H stage loads -> S MFMAs+exp (hides latency) -> barrier ->
//           write Et + Hs -> barrier -> O phase (LDS reads + 36 MFMAs).
// ---------------------------------------------------------------------------
__global__ __launch_bounds__(256) void attn_kernel(
    const unsigned short* __restrict__ f_t, const unsigned short* __restrict__ g_t,
    const unsigned short* __restrict__ h,   const float* __restrict__ Lsum,
    float* __restrict__ P)
{
    const int b  = blockIdx.y;
    const int m0 = blockIdx.x * 128;
    const int kz = blockIdx.z;
    const int tid = threadIdx.x;
    const int lane = tid & 63, w = tid >> 6;
    const int l15 = lane & 15, lg = lane >> 4;

    __shared__ unsigned short Hs[144 * 64];    // 18 KB, swizzled 16B chunks
    __shared__ unsigned short Et[4 * 2048];    // 16 KB, per-wave slices
    unsigned short* et = &Et[w * 2048];
    const int swzx = (l15 & 7) << 3;

    const f32x4 zero = {0.f, 0.f, 0.f, 0.f};

    // persistent F B-frags for this wave's 2 m-tiles (own 32 m)
    bf16x8 fF[2];
    #pragma unroll
    for (int mt = 0; mt < 2; ++mt)
        fF[mt] = *(const bf16x8*)&f_t[((size_t)b * MM + m0 + w * 32 + mt * 16 + l15) * 32 + lg * 8];

    f32x4 acc[9][2];
    #pragma unroll
    for (int ct = 0; ct < 9; ++ct)
        #pragma unroll
        for (int mt = 0; mt < 2; ++mt) acc[ct][mt] = zero;

    const int kbeg = kz * (MM / 2), kend = kbeg + (MM / 2);
    for (int kc = kbeg; kc < kend; kc += 64) {
        // ---- issue H-chunk staging loads (global -> regs), latency hidden
        //      under the S phase below ------------------------------------
        bf16x8 hst[5];
        #pragma unroll
        for (int u = 0; u < 5; ++u) {
            int idx = tid + u * 256;            // 1152 chunks = 144 rows x 8
            int c = idx >> 3, seg = idx & 7;
            bf16x8 v = {0,0,0,0,0,0,0,0};
            if (idx < 1152 && c < CIN)
                v = *(const bf16x8*)&h[((size_t)b * CIN + c) * MM + kc + seg * 8];
            hst[u] = v;
        }

        // ---- S phase: own-m S for all 4 k-tiles (8 MFMAs) ----------------
        bf16x8 aG[4];
        #pragma unroll
        for (int kt = 0; kt < 4; ++kt)
            aG[kt] = *(const bf16x8*)&g_t[((size_t)b * MM + kc + kt * 16 + l15) * 32 + lg * 8];
        f32x4 rv[4];
        #pragma unroll
        for (int kt = 0; kt < 4; ++kt) {
            f32x4 ls = *(const f32x4*)&Lsum[b * MM + kc + kt * 16 + lg * 4];
            #pragma unroll
            for (int r = 0; r < 4; ++r) rv[kt][r] = __builtin_amdgcn_rcpf(ls[r]);
        }
        u16x4 epk[2][4];
        #pragma unroll
        for (int mt = 0; mt < 2; ++mt) {
            #pragma unroll
            for (int kt = 0; kt < 4; ++kt) {
                f32x4 s = MFMA16(aG[kt], fF[mt], zero);
                #pragma unroll
                for (int r = 0; r < 4; ++r)
                    epk[mt][kt][r] = f2bf(__expf(s[r] - 4.0f) * rv[kt][r]);
            }
        }

        __syncthreads();   // all waves done reading prev Et/Hs

        // ---- write Et (own slice) + Hs (staged regs) ---------------------
        #pragma unroll
        for (int mt = 0; mt < 2; ++mt)
            #pragma unroll
            for (int kt = 0; kt < 4; ++kt)
                *(u16x4*)&et[(mt * 16 + l15) * 64 + ((kt * 16 + lg * 4) ^ swzx)] = epk[mt][kt];
        #pragma unroll
        for (int u = 0; u < 5; ++u) {
            int idx = tid + u * 256;
            int c = idx >> 3, seg = idx & 7;
            if (idx < 1152)
                *(bf16x8*)&Hs[(size_t)c * 64 + (seg ^ (c & 7)) * 8] = hst[u];
        }

        __syncthreads();   // Et/Hs visible to all

        // ---- O phase: 36 MFMAs from swizzled LDS -------------------------
        bf16x8 eB[2][2];
        #pragma unroll
        for (int mt = 0; mt < 2; ++mt)
            #pragma unroll
            for (int ks = 0; ks < 2; ++ks)
                eB[mt][ks] = *(const bf16x8*)&et[(mt * 16 + l15) * 64 + ((ks * 32 + lg * 8) ^ swzx)];

        #pragma unroll
        for (int ct = 0; ct < 9; ++ct) {
            const int row = ct * 16 + l15;      // rows >= CIN hold zeros
            #pragma unroll
            for (int ks = 0; ks < 2; ++ks) {
                bf16x8 aH = *(const bf16x8*)&Hs[(size_t)row * 64 + (((ks * 4 + lg) ^ (row & 7)) * 8)];
                #pragma unroll
                for (int mt = 0; mt < 2; ++mt)
                    acc[ct][mt] = MFMA16(aH, eB[mt][ks], acc[ct][mt]);
            }
        }
    }

    // partial store: P[kz][b][c][m]
    #pragma unroll
    for (int ct = 0; ct < 9; ++ct) {
        #pragma unroll
        for (int mt = 0; mt < 2; ++mt) {
            const int m = m0 + w * 32 + mt * 16 + l15;
            #pragma unroll
            for (int r = 0; r < 4; ++r) {
                const int c = ct * 16 + lg * 4 + r;
                if (c < CIN)
                    P[((size_t)(kz * BB + b) * CIN + c) * MM + m] = acc[ct][mt][r];
            }
        }
    }
}

// ---------------------------------------------------------------------------
// K5: combine — x_t = gamma*(P0+P1) + net_t (pad cols -> 0)
// ---------------------------------------------------------------------------
__global__ __launch_bounds__(256) void combine_kernel(
    const float* __restrict__ P, const unsigned short* __restrict__ net_t,
    const float* __restrict__ gamma_p, unsigned short* __restrict__ x_t)
{
    const int b = blockIdx.y;
    const int moff = threadIdx.x & 63, cg = threadIdx.x >> 6;
    const int m = blockIdx.x * 64 + moff;
    const float gam = gamma_p[0];

    #pragma unroll
    for (int j = 0; j < 5; ++j) {
        const int c0 = cg * 40 + j * 8;
        u16x8 net8 = *(const u16x8*)&net_t[((size_t)b * MM + m) * CIN_P + c0];
        u16x8 pk;
        #pragma unroll
        for (int i = 0; i < 8; ++i) {
            const int c = c0 + i;
            if (c < CIN) {
                float p0 = P[((size_t)(0 * BB + b) * CIN + c) * MM + m];
                float p1 = P[((size_t)(1 * BB + b) * CIN + c) * MM + m];
                pk[i] = f2bf(gam * (p0 + p1) + bf2f(net8[i]));
            } else {
                pk[i] = 0;
            }
        }
        *(u16x8*)&x_t[((size_t)b * MM + m) * CIN_P + c0] = pk;
    }
}

// ---------------------------------------------------------------------------
// K6/K7: conv1x1 + relu via MFMA
// ---------------------------------------------------------------------------
template <int KS, int OT, bool OUTF32>
__global__ __launch_bounds__(256) void conv_mfma_kernel(
    const unsigned short* __restrict__ Wb, const float* __restrict__ bias,
    const unsigned short* __restrict__ in_t,
    unsigned short* __restrict__ out_bf, float* __restrict__ out_f32)
{
    const int CINP = KS * 32;
    const int lane = threadIdx.x & 63, w = threadIdx.x >> 6;
    const int l15 = lane & 15, lg = lane >> 4;
    const int m = blockIdx.x * 64 + w * 16 + l15;   // over B*M

    bf16x8 bFr[KS];
    #pragma unroll
    for (int ks = 0; ks < KS; ++ks)
        bFr[ks] = *(const bf16x8*)&in_t[(size_t)m * CINP + ks * 32 + lg * 8];

    const f32x4 zero = {0.f, 0.f, 0.f, 0.f};

    #pragma unroll
    for (int ot = 0; ot < OT; ++ot) {
        f32x4 acc = zero;
        #pragma unroll
        for (int ks = 0; ks < KS; ++ks) {
            bf16x8 aW = *(const bf16x8*)&Wb[(size_t)(ot * 16 + l15) * CINP + ks * 32 + lg * 8];
            acc = MFMA16(aW, bFr[ks], acc);
        }
        const int obase = ot * 16 + lg * 4;
        if (OUTF32) {
            const int bb = m >> 12, mm = m & (MM - 1);
            #pragma unroll
            for (int r = 0; r < 4; ++r)
                out_f32[((size_t)bb * (OT * 16) + obase + r) * MM + mm] =
                    fmaxf(acc[r] + bias[obase + r], 0.f);
        } else {
            u16x4 pk;
            #pragma unroll
            for (int r = 0; r < 4; ++r)
                pk[r] = f2bf(fmaxf(acc[r] + bias[obase + r], 0.f));
            *(u16x4*)&out_bf[(size_t)m * (OT * 16) + obase] = pk;
        }
    }
}

// ---------------------------------------------------------------------------
extern "C" void kernel_launch(void* const* d_in, const int* in_sizes, int n_in,
                              void* d_out, int out_size, void* d_ws, size_t ws_size,
                              hipStream_t stream)
{
    const float* inp   = (const float*)d_in[0];
    const float* WF    = (const float*)d_in[1];
    const float* bF    = (const float*)d_in[2];
    const float* WG    = (const float*)d_in[3];
    const float* bG    = (const float*)d_in[4];
    const float* WH    = (const float*)d_in[5];
    const float* bH    = (const float*)d_in[6];
    const float* gamma = (const float*)d_in[7];
    const float* W1    = (const float*)d_in[8];
    const float* b1    = (const float*)d_in[9];
    const float* W2    = (const float*)d_in[10];
    const float* b2    = (const float*)d_in[11];
    float* out = (float*)d_out;

    char* p = (char*)d_ws;
    auto alloc = [&](size_t bytes) { char* q = p; p += (bytes + 255) & ~(size_t)255; return q; };
    unsigned short* net_t = (unsigned short*)alloc((size_t)BB * MM * CIN_P * 2);  // 10.5 MB
    unsigned short* f_t   = (unsigned short*)alloc((size_t)BB * MM * 32 * 2);     //  2.1 MB
    unsigned short* g_t   = (unsigned short*)alloc((size_t)BB * MM * 32 * 2);     //  2.1 MB
    unsigned short* h     = (unsigned short*)alloc((size_t)BB * CIN * MM * 2);    //  8.5 MB
    float*          Lsum  = (float*)alloc((size_t)BB * MM * 4);                   //  0.13 MB
    unsigned short* x_t   = (unsigned short*)alloc((size_t)BB * MM * CIN_P * 2);  // 10.5 MB
    float*          P     = (float*)alloc((size_t)2 * BB * CIN * MM * 4);         // 34.1 MB
    unsigned short* x1_t  = (unsigned short*)P;   // alias: P dead after combine
    unsigned short* W1b   = (unsigned short*)alloc((size_t)256 * CIN_P * 2);
    unsigned short* W2b   = (unsigned short*)alloc((size_t)128 * 256 * 2);
    unsigned short* Wfgh  = (unsigned short*)alloc((size_t)OPAD * CIN_P * 2);
    float*          bfgh  = (float*)alloc((size_t)OPAD * 4);

    prep_kernel<<<547, 256, 0, stream>>>(W1, W2, WF, WG, WH, bF, bG, bH,
                                         W1b, W2b, Wfgh, bfgh, Lsum);

    transpose_kernel<<<dim3(NN / 32, BB), 256, 0, stream>>>(inp, net_t);

    proj_kernel<<<dim3(BB * MM / 64), 256, 0, stream>>>(
        Wfgh, bfgh, net_t, f_t, g_t, h);

    rowstats_kernel<<<dim3(MM / 64, BB, 4), 256, 0, stream>>>(f_t, g_t, Lsum);

    attn_kernel<<<dim3(MM / 128, BB, 2), 256, 0, stream>>>(f_t, g_t, h, Lsum, P);

    combine_kernel<<<dim3(MM / 64, BB), 256, 0, stream>>>(P, net_t, gamma, x_t);

    conv_mfma_kernel<5, 16, false><<<dim3(BB * MM / 64), 256, 0, stream>>>(
        W1b, b1, x_t, x1_t, nullptr);

    conv_mfma_kernel<8, 8, true><<<dim3(BB * MM / 64), 256, 0, stream>>>(
        W2b, b2, x1_t, nullptr, out);
}